// Round 1
// baseline (995.701 us; speedup 1.0000x reference)
//
#include <hip/hip_runtime.h>
#include <hip/hip_bf16.h>

// B=8 H=8 N=64 T=256 E=512 D=64 DH=64, TAU=1 -> scale 1/8
// Pipeline (reordered, exact same math as reference):
//   Qh = head-split(q@Wq^T), Kh = head-split(k@Wk^T)
//   attnT[b,h,j,i] = softmax_j(Qh.Kh^T/8)
//   v'[b,h,j,s,d]  = sum_dd Wcat[d, h*64+dd] * v[b,h,j,s,dd]      (Wcat moved first; commutes)
//   V'[b,h,j,t,d]  = sum_{s<=t} Wconv[h,j,t,s] * v'[b,h,j,s,d]    (stored bf16 in ws)
//   out[b,i,t,d]   = sum_{h,j} attnT[b,h,j,i] * V'[b,h,j,t,d]     (one 64x16384x512 GEMM per b)

typedef unsigned short u16;
typedef unsigned int u32;

static __device__ __forceinline__ float bf2f(u16 u) {
    u32 x = ((u32)u) << 16;
    float f; __builtin_memcpy(&f, &x, 4); return f;
}
static __device__ __forceinline__ u16 f2bf(float f) {
    u32 x; __builtin_memcpy(&x, &f, 4);
    u32 r = (x + 0x7fffu + ((x >> 16) & 1u)) >> 16;  // RNE
    return (u16)r;
}

// ---------------- K1: Q/K projection, C = X(512x512) @ W^T, head-split store ----
__global__ __launch_bounds__(256) void proj_qk(
        const float* __restrict__ q, const float* __restrict__ k,
        const float* __restrict__ Wq, const float* __restrict__ Wk,
        float* __restrict__ Qh, float* __restrict__ Kh) {
    const int et = blockIdx.x, rt = blockIdx.y, z = blockIdx.z;
    const float* X = z ? k : q;
    const float* W = z ? Wk : Wq;
    float* Out = z ? Kh : Qh;
    __shared__ float Xs[32][65];
    __shared__ float Ws[32][65];
    const int tid = threadIdx.x;
    const int tx = tid & 15, ty = tid >> 4;
    const int r0 = rt * 64, e0 = et * 64;
    float acc[4][4] = {};
    for (int k0 = 0; k0 < 512; k0 += 32) {
        __syncthreads();
        #pragma unroll
        for (int rep = 0; rep < 8; ++rep) {
            int lin = rep * 256 + tid;
            int kk = lin & 31, m = lin >> 5;
            Xs[kk][m] = X[(size_t)(r0 + m) * 512 + k0 + kk];
            Ws[kk][m] = W[(size_t)(e0 + m) * 512 + k0 + kk];
        }
        __syncthreads();
        #pragma unroll 8
        for (int kk = 0; kk < 32; ++kk) {
            float a0 = Xs[kk][4 * ty + 0], a1 = Xs[kk][4 * ty + 1];
            float a2 = Xs[kk][4 * ty + 2], a3 = Xs[kk][4 * ty + 3];
            float b0 = Ws[kk][4 * tx + 0], b1 = Ws[kk][4 * tx + 1];
            float b2 = Ws[kk][4 * tx + 2], b3 = Ws[kk][4 * tx + 3];
            acc[0][0] += a0 * b0; acc[0][1] += a0 * b1; acc[0][2] += a0 * b2; acc[0][3] += a0 * b3;
            acc[1][0] += a1 * b0; acc[1][1] += a1 * b1; acc[1][2] += a1 * b2; acc[1][3] += a1 * b3;
            acc[2][0] += a2 * b0; acc[2][1] += a2 * b1; acc[2][2] += a2 * b2; acc[2][3] += a2 * b3;
            acc[3][0] += a3 * b0; acc[3][1] += a3 * b1; acc[3][2] += a3 * b2; acc[3][3] += a3 * b3;
        }
    }
    #pragma unroll
    for (int i = 0; i < 4; ++i) {
        #pragma unroll
        for (int j = 0; j < 4; ++j) {
            int r = r0 + 4 * ty + i;   // b*64 + n
            int e = e0 + 4 * tx + j;   // h*64 + dh
            int b = r >> 6, n = r & 63, h = e >> 6, dh = e & 63;
            Out[(((size_t)(b * 8 + h) * 64 + n) * 64) + dh] = acc[i][j];
        }
    }
}

// ---------------- K2: scores + softmax -> attnT[b,h,j,i] -------------------------
__global__ __launch_bounds__(256) void attn_softmax(
        const float* __restrict__ Qh, const float* __restrict__ Kh,
        float* __restrict__ attnT) {
    const int bh = blockIdx.x;          // b*8+h
    const int tid = threadIdx.x;
    __shared__ float Qt[64][64];
    __shared__ float KT[64][65];
    const size_t base = (size_t)bh * 4096;
    #pragma unroll
    for (int rep = 0; rep < 16; ++rep) {
        int lin = rep * 256 + tid;
        int r = lin >> 6, c = lin & 63;
        Qt[r][c] = Qh[base + lin];
        KT[c][r] = Kh[base + lin];
    }
    __syncthreads();
    const int w = tid >> 6, lane = tid & 63;
    for (int rr = 0; rr < 16; ++rr) {
        int i = w + 4 * rr;
        float s = 0.f;
        #pragma unroll
        for (int dd = 0; dd < 64; ++dd) s += Qt[i][dd] * KT[dd][lane];
        s *= 0.125f;                      // 1/(TAU*sqrt(DH))
        float m = s;
        #pragma unroll
        for (int off = 32; off; off >>= 1) m = fmaxf(m, __shfl_xor(m, off));
        float e = __expf(s - m);
        float sum = e;
        #pragma unroll
        for (int off = 32; off; off >>= 1) sum += __shfl_xor(sum, off);
        attnT[base + (size_t)lane * 64 + i] = e / sum;   // [j][i]
    }
}

// ---------------- K3: v' = Wcat_h @ v, then V' = tril(Wconv) @ v'  (bf16 out) ----
__global__ __launch_bounds__(256) void conv_vp(
        const float* __restrict__ v, const float* __restrict__ Wconv,
        const float* __restrict__ Wcat, u16* __restrict__ Vp, int bbase) {
    const int bl = blockIdx.x;                 // local b within chunk
    const int b = bbase + bl;
    const int hj = blockIdx.y;                 // h*64 + j
    const int h = hj >> 6;
    const int tid = threadIdx.x;
    const int w = __builtin_amdgcn_readfirstlane(tid >> 6);  // wave id (scalar)
    const int d = tid & 63;

    __shared__ float vs[64][64];               // 16 KB: 64-row chunk of v
    __shared__ u16 vpt[64][256];               // 32 KB: v' transposed [d][s], XOR-swizzled

    // per-lane Wcat row: wr[dd] = Wcat[d, h*64+dd]
    float wr[64];
    #pragma unroll
    for (int q4 = 0; q4 < 16; ++q4) {
        float4 t4 = *(const float4*)&Wcat[(size_t)d * 512 + h * 64 + q4 * 4];
        wr[q4 * 4 + 0] = t4.x; wr[q4 * 4 + 1] = t4.y;
        wr[q4 * 4 + 2] = t4.z; wr[q4 * 4 + 3] = t4.w;
    }

    const size_t vbase = (size_t)(((b * 8 + h) * 64) + (hj & 63)) * 16384;

    // phase 1+2: stage v chunk, compute v' rows, write swizzled bf16 transpose
    for (int c = 0; c < 4; ++c) {
        if (c) __syncthreads();
        #pragma unroll
        for (int rep = 0; rep < 16; ++rep) {
            int lin = rep * 256 + tid;
            int sl = lin >> 6, dd = lin & 63;
            vs[sl][dd] = v[vbase + (size_t)(c * 64 + sl) * 64 + dd];
        }
        __syncthreads();
        #pragma unroll
        for (int kk = 0; kk < 8; ++kk) {
            int sA = w + 8 * kk, sB = sA + 4;
            float a0 = 0.f, a1 = 0.f;
            #pragma unroll
            for (int dd = 0; dd < 64; ++dd) {
                a0 += vs[sA][dd] * wr[dd];
                a1 += vs[sB][dd] * wr[dd];
            }
            int gA = c * 64 + sA, gB = c * 64 + sB;
            vpt[d][(((gA >> 3) ^ (d & 7)) << 3) + (gA & 7)] = f2bf(a0);
            vpt[d][(((gB >> 3) ^ (d & 7)) << 3) + (gB & 7)] = f2bf(a1);
        }
    }
    __syncthreads();

    // phase 3: causal conv. wave w handles t-octets oct = w+4p, rows t = oct*8+i.
    const float* wcb = Wconv + (size_t)hj * 65536;
    u16* vout = Vp + ((size_t)bl * 512 + hj) * 16384;
    for (int p = 0; p < 8; ++p) {
        int oct = w + 4 * p;
        float acc[8] = {};
        float vp[8];
        for (int sc = 0; sc < oct; ++sc) {     // full 8-wide s-chunks
            uint4 raw = *(const uint4*)&vpt[d][(sc ^ (d & 7)) << 3];
            vp[0] = __uint_as_float(raw.x << 16); vp[1] = __uint_as_float(raw.x & 0xffff0000u);
            vp[2] = __uint_as_float(raw.y << 16); vp[3] = __uint_as_float(raw.y & 0xffff0000u);
            vp[4] = __uint_as_float(raw.z << 16); vp[5] = __uint_as_float(raw.z & 0xffff0000u);
            vp[6] = __uint_as_float(raw.w << 16); vp[7] = __uint_as_float(raw.w & 0xffff0000u);
            #pragma unroll
            for (int i = 0; i < 8; ++i) {
                const float4* wrow = (const float4*)(wcb + (size_t)(oct * 8 + i) * 256 + sc * 8);
                float4 wa = wrow[0], wb = wrow[1];
                acc[i] += wa.x * vp[0] + wa.y * vp[1] + wa.z * vp[2] + wa.w * vp[3]
                        + wb.x * vp[4] + wb.y * vp[5] + wb.z * vp[6] + wb.w * vp[7];
            }
        }
        {   // triangular tail chunk sc == oct
            uint4 raw = *(const uint4*)&vpt[d][(oct ^ (d & 7)) << 3];
            vp[0] = __uint_as_float(raw.x << 16); vp[1] = __uint_as_float(raw.x & 0xffff0000u);
            vp[2] = __uint_as_float(raw.y << 16); vp[3] = __uint_as_float(raw.y & 0xffff0000u);
            vp[4] = __uint_as_float(raw.z << 16); vp[5] = __uint_as_float(raw.z & 0xffff0000u);
            vp[6] = __uint_as_float(raw.w << 16); vp[7] = __uint_as_float(raw.w & 0xffff0000u);
            #pragma unroll
            for (int i = 0; i < 8; ++i) {
                const float* wrow = wcb + (size_t)(oct * 8 + i) * 256 + oct * 8;
                #pragma unroll
                for (int si = 0; si < 8; ++si)
                    if (si <= i) acc[i] += wrow[si] * vp[si];
            }
        }
        #pragma unroll
        for (int i = 0; i < 8; ++i)
            vout[(size_t)(oct * 8 + i) * 64 + d] = f2bf(acc[i]);
    }
}

// ---------------- K4: out[b] = A[b](64x512) @ V'[b](512x16384) -------------------
__global__ __launch_bounds__(256) void final_gemm(
        const float* __restrict__ attnT, const u16* __restrict__ Vp,
        float* __restrict__ out, int bbase) {
    const int tdt = blockIdx.x;        // td tile of 256
    const int bl = blockIdx.y;
    const int b = bbase + bl;
    const int tid = threadIdx.x;
    const int td = tdt * 256 + tid;
    float acc[64] = {};
    const float* ab = attnT + (size_t)b * 32768;          // b*512*64
    const u16* vb = Vp + (size_t)bl * 512 * 16384 + td;
    for (int hj = 0; hj < 512; ++hj) {
        float vv = bf2f(vb[(size_t)hj * 16384]);
        const float4* ac4 = (const float4*)(ab + (size_t)hj * 64);
        #pragma unroll
        for (int q4 = 0; q4 < 16; ++q4) {
            float4 a4 = ac4[q4];
            acc[q4 * 4 + 0] += a4.x * vv;
            acc[q4 * 4 + 1] += a4.y * vv;
            acc[q4 * 4 + 2] += a4.z * vv;
            acc[q4 * 4 + 3] += a4.w * vv;
        }
    }
    float* ob = out + (size_t)b * 64 * 16384 + td;
    #pragma unroll
    for (int ii = 0; ii < 64; ++ii)
        ob[(size_t)ii * 16384] = acc[ii];
}

extern "C" void kernel_launch(void* const* d_in, const int* in_sizes, int n_in,
                              void* d_out, int out_size, void* d_ws, size_t ws_size,
                              hipStream_t stream) {
    const float* q     = (const float*)d_in[0];
    const float* k     = (const float*)d_in[1];
    const float* v     = (const float*)d_in[2];
    const float* Wq    = (const float*)d_in[3];
    const float* Wk    = (const float*)d_in[4];
    const float* Wconv = (const float*)d_in[5];
    const float* Wcat  = (const float*)d_in[6];
    float* out = (float*)d_out;

    // ws layout: attnT (1MB) | Qh (1MB) | Kh (1MB) | V' bf16 (up to 128MB)
    float* attnT = (float*)d_ws;
    float* Qh = attnT + 262144;
    float* Kh = Qh + 262144;
    u16* Vp = (u16*)(Kh + 262144);
    const size_t fixed = (size_t)3 * 262144 * 4;

    int bc = 8;  // batches per chunk; shrink if ws too small
    while (bc > 1 && fixed + (size_t)bc * 512 * 16384 * 2 > ws_size) bc >>= 1;

    proj_qk<<<dim3(8, 8, 2), 256, 0, stream>>>(q, k, Wq, Wk, Qh, Kh);
    attn_softmax<<<64, 256, 0, stream>>>(Qh, Kh, attnT);
    for (int b0 = 0; b0 < 8; b0 += bc) {
        conv_vp<<<dim3(bc, 512), 256, 0, stream>>>(v, Wconv, Wcat, Vp, b0);
        final_gemm<<<dim3(64, bc), 256, 0, stream>>>(attnT, Vp, out, b0);
    }
}

// Round 2
// 471.127 us; speedup vs baseline: 2.1134x; 2.1134x over previous
//
#include <hip/hip_runtime.h>
#include <hip/hip_bf16.h>

// B=8 H=8 N=64 T=256 E=512 D=64 DH=64, TAU=1 -> scale 1/8
// Pipeline (reordered, exact same math as reference):
//   Qh = head-split(q@Wq^T), Kh = head-split(k@Wk^T)
//   attnT[b,h,j,i] = softmax_j(Qh.Kh^T/8)
//   v'[b,h,j,s,d]  = sum_dd Wcat[d, h*64+dd] * v[b,h,j,s,dd]      (Wcat moved first; commutes)
//   V'[b,h,j,t,d]  = sum_{s<=t} Wconv[h,j,t,s] * v'[b,h,j,s,d]    (bf16 MFMA, stored bf16 in ws)
//   out[b,i,t,d]   = sum_{h,j} attnT[b,h,j,i] * V'[b,h,j,t,d]

typedef unsigned short u16;
typedef unsigned int u32;
typedef __attribute__((ext_vector_type(8))) short short8;
typedef __attribute__((ext_vector_type(4))) float f32x4;

static __device__ __forceinline__ float bf2f(u16 u) {
    u32 x = ((u32)u) << 16;
    float f; __builtin_memcpy(&f, &x, 4); return f;
}
static __device__ __forceinline__ u16 f2bf(float f) {
    u32 x; __builtin_memcpy(&x, &f, 4);
    u32 r = (x + 0x7fffu + ((x >> 16) & 1u)) >> 16;  // RNE
    return (u16)r;
}
static __device__ __forceinline__ short8 pack8(float4 a, float4 b) {
    short8 r;
    r[0] = (short)f2bf(a.x); r[1] = (short)f2bf(a.y);
    r[2] = (short)f2bf(a.z); r[3] = (short)f2bf(a.w);
    r[4] = (short)f2bf(b.x); r[5] = (short)f2bf(b.y);
    r[6] = (short)f2bf(b.z); r[7] = (short)f2bf(b.w);
    return r;
}

// ---------------- K1: Q/K projection, C = X(512x512) @ W^T, head-split store ----
__global__ __launch_bounds__(256) void proj_qk(
        const float* __restrict__ q, const float* __restrict__ k,
        const float* __restrict__ Wq, const float* __restrict__ Wk,
        float* __restrict__ Qh, float* __restrict__ Kh) {
    const int et = blockIdx.x, rt = blockIdx.y, z = blockIdx.z;
    const float* X = z ? k : q;
    const float* W = z ? Wk : Wq;
    float* Out = z ? Kh : Qh;
    __shared__ float Xs[32][65];
    __shared__ float Ws[32][65];
    const int tid = threadIdx.x;
    const int tx = tid & 15, ty = tid >> 4;
    const int r0 = rt * 64, e0 = et * 64;
    float acc[4][4] = {};
    for (int k0 = 0; k0 < 512; k0 += 32) {
        __syncthreads();
        #pragma unroll
        for (int rep = 0; rep < 8; ++rep) {
            int lin = rep * 256 + tid;
            int kk = lin & 31, m = lin >> 5;
            Xs[kk][m] = X[(size_t)(r0 + m) * 512 + k0 + kk];
            Ws[kk][m] = W[(size_t)(e0 + m) * 512 + k0 + kk];
        }
        __syncthreads();
        #pragma unroll 8
        for (int kk = 0; kk < 32; ++kk) {
            float a0 = Xs[kk][4 * ty + 0], a1 = Xs[kk][4 * ty + 1];
            float a2 = Xs[kk][4 * ty + 2], a3 = Xs[kk][4 * ty + 3];
            float b0 = Ws[kk][4 * tx + 0], b1 = Ws[kk][4 * tx + 1];
            float b2 = Ws[kk][4 * tx + 2], b3 = Ws[kk][4 * tx + 3];
            acc[0][0] += a0 * b0; acc[0][1] += a0 * b1; acc[0][2] += a0 * b2; acc[0][3] += a0 * b3;
            acc[1][0] += a1 * b0; acc[1][1] += a1 * b1; acc[1][2] += a1 * b2; acc[1][3] += a1 * b3;
            acc[2][0] += a2 * b0; acc[2][1] += a2 * b1; acc[2][2] += a2 * b2; acc[2][3] += a2 * b3;
            acc[3][0] += a3 * b0; acc[3][1] += a3 * b1; acc[3][2] += a3 * b2; acc[3][3] += a3 * b3;
        }
    }
    #pragma unroll
    for (int i = 0; i < 4; ++i) {
        #pragma unroll
        for (int j = 0; j < 4; ++j) {
            int r = r0 + 4 * ty + i;   // b*64 + n
            int e = e0 + 4 * tx + j;   // h*64 + dh
            int b = r >> 6, n = r & 63, h = e >> 6, dh = e & 63;
            Out[(((size_t)(b * 8 + h) * 64 + n) * 64) + dh] = acc[i][j];
        }
    }
}

// ---------------- K2: scores + softmax -> attnT[b,h,j,i] -------------------------
__global__ __launch_bounds__(256) void attn_softmax(
        const float* __restrict__ Qh, const float* __restrict__ Kh,
        float* __restrict__ attnT) {
    const int bh = blockIdx.x;          // b*8+h
    const int tid = threadIdx.x;
    __shared__ float Qt[64][64];
    __shared__ float KT[64][65];
    const size_t base = (size_t)bh * 4096;
    #pragma unroll
    for (int rep = 0; rep < 16; ++rep) {
        int lin = rep * 256 + tid;
        int r = lin >> 6, c = lin & 63;
        Qt[r][c] = Qh[base + lin];
        KT[c][r] = Kh[base + lin];
    }
    __syncthreads();
    const int w = tid >> 6, lane = tid & 63;
    for (int rr = 0; rr < 16; ++rr) {
        int i = w + 4 * rr;
        float s = 0.f;
        #pragma unroll
        for (int dd = 0; dd < 64; ++dd) s += Qt[i][dd] * KT[dd][lane];
        s *= 0.125f;                      // 1/(TAU*sqrt(DH))
        float m = s;
        #pragma unroll
        for (int off = 32; off; off >>= 1) m = fmaxf(m, __shfl_xor(m, off));
        float e = __expf(s - m);
        float sum = e;
        #pragma unroll
        for (int off = 32; off; off >>= 1) sum += __shfl_xor(sum, off);
        attnT[base + (size_t)lane * 64 + i] = e / sum;   // [j][i]
    }
}

// ---------------- K3: MFMA conv: v' = v@Wcat_h^T (LDS), V' = tril(Wconv)@v' ------
__global__ __launch_bounds__(256) void conv_mfma(
        const float* __restrict__ v, const float* __restrict__ Wconv,
        const float* __restrict__ Wcat, u16* __restrict__ Vp, int bbase) {
    const int bl = blockIdx.x, b = bbase + bl;
    const int hj = blockIdx.y, h = hj >> 6, j = hj & 63;
    const int tid = threadIdx.x;
    const int w = tid >> 6;            // wave id 0..3
    const int l = tid & 63;
    const int lo = l & 15, hi = l >> 4;

    // v' transposed [d][s] bf16, 16B-chunk XOR-swizzled: chunk' = (s>>3) ^ (d&7)
    __shared__ u16 vptB[64 * 256];     // 32 KB

    const size_t vbase = ((size_t)(b * 8 + h) * 64 + j) * 16384;

    // ---- Phase A: v'(256x64) = v(256x64) @ Wcat_h^T(64x64), MFMA 16x16x32 ----
    {
        f32x4 accA[4][4] = {};         // [s-tile][d-tile]; wave w owns s in [w*64, w*64+64)
        #pragma unroll
        for (int kk = 0; kk < 2; ++kk) {
            short8 bfr[4];
            #pragma unroll
            for (int di = 0; di < 4; ++di) {
                const float* p = Wcat + (size_t)(di * 16 + lo) * 512 + h * 64 + kk * 32 + hi * 8;
                bfr[di] = pack8(((const float4*)p)[0], ((const float4*)p)[1]);
            }
            #pragma unroll
            for (int si = 0; si < 4; ++si) {
                const float* p = v + vbase + (size_t)(w * 64 + si * 16 + lo) * 64 + kk * 32 + hi * 8;
                short8 af = pack8(((const float4*)p)[0], ((const float4*)p)[1]);
                #pragma unroll
                for (int di = 0; di < 4; ++di)
                    accA[si][di] = __builtin_amdgcn_mfma_f32_16x16x32_bf16(af, bfr[di], accA[si][di], 0, 0, 0);
            }
        }
        // write C transposed into vptB: s = w*64+si*16+hi*4+r, d = di*16+lo
        #pragma unroll
        for (int si = 0; si < 4; ++si) {
            int s0 = w * 64 + si * 16 + hi * 4;      // 4 consecutive s (s0 % 4 == 0)
            #pragma unroll
            for (int di = 0; di < 4; ++di) {
                int d = di * 16 + lo;
                u32 lo32 = (u32)f2bf(accA[si][di][0]) | ((u32)f2bf(accA[si][di][1]) << 16);
                u32 hi32 = (u32)f2bf(accA[si][di][2]) | ((u32)f2bf(accA[si][di][3]) << 16);
                u16* dst = &vptB[d * 256 + (((s0 >> 3) ^ (d & 7)) << 3) + (s0 & 7)];
                ((uint2*)dst)[0] = make_uint2(lo32, hi32);   // ds_write_b64
            }
        }
    }
    __syncthreads();

    // ---- Phase B: V'(256x64) = tril(Wconv_hj)(256x256) @ v'(256x64) ----
    // wave w owns t-tiles ti in {w, w+4, w+8, w+12} (balanced causal triangle)
    f32x4 acc[4][4] = {};              // [slot][d-tile]
    const float* wcb = Wconv + (size_t)hj * 65536;
    for (int kk = 0; kk < 8; ++kk) {   // s-chunk of 32
        if (2 * kk > w + 12) break;    // no active tile for this wave
        short8 bfr[4];
        #pragma unroll
        for (int di = 0; di < 4; ++di) {
            int d = di * 16 + lo;
            int sc = kk * 4 + hi;      // 8-wide s-chunk index
            bfr[di] = *(const short8*)&vptB[d * 256 + ((sc ^ (d & 7)) << 3)];  // ds_read_b128
        }
        #pragma unroll
        for (int slot = 0; slot < 4; ++slot) {
            int ti = w + slot * 4;
            if (ti < 2 * kk) continue;               // s_min > t_max: skip
            int t = ti * 16 + lo;
            const float* p = wcb + (size_t)t * 256 + kk * 32 + hi * 8;
            float4 x = ((const float4*)p)[0], y = ((const float4*)p)[1];
            float wf[8] = {x.x, x.y, x.z, x.w, y.x, y.y, y.z, y.w};
            if (ti <= 2 * kk + 1) {                  // diagonal chunk: mask s > t
                int sb = kk * 32 + hi * 8;
                #pragma unroll
                for (int e = 0; e < 8; ++e)
                    if (sb + e > t) wf[e] = 0.f;
            }
            short8 af;
            af[0] = (short)f2bf(wf[0]); af[1] = (short)f2bf(wf[1]);
            af[2] = (short)f2bf(wf[2]); af[3] = (short)f2bf(wf[3]);
            af[4] = (short)f2bf(wf[4]); af[5] = (short)f2bf(wf[5]);
            af[6] = (short)f2bf(wf[6]); af[7] = (short)f2bf(wf[7]);
            #pragma unroll
            for (int di = 0; di < 4; ++di)
                acc[slot][di] = __builtin_amdgcn_mfma_f32_16x16x32_bf16(af, bfr[di], acc[slot][di], 0, 0, 0);
        }
    }

    // write V' (bf16) to ws: vout[t*64 + d]
    u16* vout = Vp + ((size_t)bl * 512 + hj) * 16384;
    #pragma unroll
    for (int slot = 0; slot < 4; ++slot) {
        int ti = w + slot * 4;
        int t0 = ti * 16 + hi * 4;
        #pragma unroll
        for (int di = 0; di < 4; ++di) {
            int d = di * 16 + lo;
            #pragma unroll
            for (int r = 0; r < 4; ++r)
                vout[(size_t)(t0 + r) * 64 + d] = f2bf(acc[slot][di][r]);
        }
    }
}

// ---------------- K4: out[b] = A[b](64x512) @ V'[b](512x16384) -------------------
__global__ __launch_bounds__(256) void final_gemm(
        const float* __restrict__ attnT, const u16* __restrict__ Vp,
        float* __restrict__ out, int bbase) {
    const int tdt = blockIdx.x;        // td tile of 256
    const int bl = blockIdx.y;
    const int b = bbase + bl;
    const int tid = threadIdx.x;
    const int td = tdt * 256 + tid;
    float acc[64] = {};
    const float* ab = attnT + (size_t)b * 32768;          // b*512*64
    const u16* vb = Vp + (size_t)bl * 512 * 16384 + td;
    for (int hj = 0; hj < 512; ++hj) {
        float vv = bf2f(vb[(size_t)hj * 16384]);
        const float4* ac4 = (const float4*)(ab + (size_t)hj * 64);
        #pragma unroll
        for (int q4 = 0; q4 < 16; ++q4) {
            float4 a4 = ac4[q4];
            acc[q4 * 4 + 0] += a4.x * vv;
            acc[q4 * 4 + 1] += a4.y * vv;
            acc[q4 * 4 + 2] += a4.z * vv;
            acc[q4 * 4 + 3] += a4.w * vv;
        }
    }
    float* ob = out + (size_t)b * 64 * 16384 + td;
    #pragma unroll
    for (int ii = 0; ii < 64; ++ii)
        ob[(size_t)ii * 16384] = acc[ii];
}

extern "C" void kernel_launch(void* const* d_in, const int* in_sizes, int n_in,
                              void* d_out, int out_size, void* d_ws, size_t ws_size,
                              hipStream_t stream) {
    const float* q     = (const float*)d_in[0];
    const float* k     = (const float*)d_in[1];
    const float* v     = (const float*)d_in[2];
    const float* Wq    = (const float*)d_in[3];
    const float* Wk    = (const float*)d_in[4];
    const float* Wconv = (const float*)d_in[5];
    const float* Wcat  = (const float*)d_in[6];
    float* out = (float*)d_out;

    // ws layout: attnT (1MB) | Qh (1MB) | Kh (1MB) | V' bf16 (up to 128MB)
    float* attnT = (float*)d_ws;
    float* Qh = attnT + 262144;
    float* Kh = Qh + 262144;
    u16* Vp = (u16*)(Kh + 262144);
    const size_t fixed = (size_t)3 * 262144 * 4;

    int bc = 8;  // batches per chunk; shrink if ws too small
    while (bc > 1 && fixed + (size_t)bc * 512 * 16384 * 2 > ws_size) bc >>= 1;

    proj_qk<<<dim3(8, 8, 2), 256, 0, stream>>>(q, k, Wq, Wk, Qh, Kh);
    attn_softmax<<<64, 256, 0, stream>>>(Qh, Kh, attnT);
    for (int b0 = 0; b0 < 8; b0 += bc) {
        conv_mfma<<<dim3(bc, 512), 256, 0, stream>>>(v, Wconv, Wcat, Vp, b0);
        final_gemm<<<dim3(64, bc), 256, 0, stream>>>(attnT, Vp, out, b0);
    }
}

// Round 3
// 297.455 us; speedup vs baseline: 3.3474x; 1.5839x over previous
//
#include <hip/hip_runtime.h>
#include <hip/hip_bf16.h>

// B=8 H=8 N=64 T=256 E=512 D=64 DH=64, TAU=1 -> scale 1/8
// Pipeline (reordered, exact same math as reference):
//   Qh = head-split(q@Wq^T), Kh = head-split(k@Wk^T)
//   Aperm[b,i,p]   = bf16 softmax_j(Qh.Kh^T/8), K-slot-permuted for MFMA frags
//   v'[b,h,j,s,d]  = sum_dd Wcat[d, h*64+dd] * v[b,h,j,s,dd]      (Wcat moved first; commutes)
//   V'[b,h,j,t,d]  = sum_{s<=t} Wconv[h,j,t,s] * v'[b,h,j,s,d]    (bf16 MFMA, stored bf16 in ws)
//   out[b,i,t,d]   = sum_{hj} A[i,hj] * V'[hj,td]  (MFMA; Vp transposed in-register via identity MFMA)

typedef unsigned short u16;
typedef unsigned int u32;
typedef __attribute__((ext_vector_type(8))) short short8;
typedef __attribute__((ext_vector_type(4))) float f32x4;

static __device__ __forceinline__ float bf2f(u16 u) {
    u32 x = ((u32)u) << 16;
    float f; __builtin_memcpy(&f, &x, 4); return f;
}
static __device__ __forceinline__ u16 f2bf(float f) {
    u32 x; __builtin_memcpy(&x, &f, 4);
    u32 r = (x + 0x7fffu + ((x >> 16) & 1u)) >> 16;  // RNE
    return (u16)r;
}
static __device__ __forceinline__ short8 pack8(float4 a, float4 b) {
    short8 r;
    r[0] = (short)f2bf(a.x); r[1] = (short)f2bf(a.y);
    r[2] = (short)f2bf(a.z); r[3] = (short)f2bf(a.w);
    r[4] = (short)f2bf(b.x); r[5] = (short)f2bf(b.y);
    r[6] = (short)f2bf(b.z); r[7] = (short)f2bf(b.w);
    return r;
}
// pack two transpose-MFMA outputs (exact bf16 in f32 high bits) into a B-frag
static __device__ __forceinline__ short8 mk_bfrag(f32x4 a, f32x4 b) {
    u32 w0 = (__float_as_uint(a[0]) >> 16) | (__float_as_uint(a[1]) & 0xffff0000u);
    u32 w1 = (__float_as_uint(a[2]) >> 16) | (__float_as_uint(a[3]) & 0xffff0000u);
    u32 w2 = (__float_as_uint(b[0]) >> 16) | (__float_as_uint(b[1]) & 0xffff0000u);
    u32 w3 = (__float_as_uint(b[2]) >> 16) | (__float_as_uint(b[3]) & 0xffff0000u);
    uint4 u = make_uint4(w0, w1, w2, w3);
    short8 r; __builtin_memcpy(&r, &u, 16); return r;
}

// ---------------- K1: Q/K projection, C = X(512x512) @ W^T, head-split store ----
__global__ __launch_bounds__(256) void proj_qk(
        const float* __restrict__ q, const float* __restrict__ k,
        const float* __restrict__ Wq, const float* __restrict__ Wk,
        float* __restrict__ Qh, float* __restrict__ Kh) {
    const int et = blockIdx.x, rt = blockIdx.y, z = blockIdx.z;
    const float* X = z ? k : q;
    const float* W = z ? Wk : Wq;
    float* Out = z ? Kh : Qh;
    __shared__ float Xs[32][65];
    __shared__ float Ws[32][65];
    const int tid = threadIdx.x;
    const int tx = tid & 15, ty = tid >> 4;
    const int r0 = rt * 64, e0 = et * 64;
    float acc[4][4] = {};
    for (int k0 = 0; k0 < 512; k0 += 32) {
        __syncthreads();
        #pragma unroll
        for (int rep = 0; rep < 8; ++rep) {
            int lin = rep * 256 + tid;
            int kk = lin & 31, m = lin >> 5;
            Xs[kk][m] = X[(size_t)(r0 + m) * 512 + k0 + kk];
            Ws[kk][m] = W[(size_t)(e0 + m) * 512 + k0 + kk];
        }
        __syncthreads();
        #pragma unroll 8
        for (int kk = 0; kk < 32; ++kk) {
            float a0 = Xs[kk][4 * ty + 0], a1 = Xs[kk][4 * ty + 1];
            float a2 = Xs[kk][4 * ty + 2], a3 = Xs[kk][4 * ty + 3];
            float b0 = Ws[kk][4 * tx + 0], b1 = Ws[kk][4 * tx + 1];
            float b2 = Ws[kk][4 * tx + 2], b3 = Ws[kk][4 * tx + 3];
            acc[0][0] += a0 * b0; acc[0][1] += a0 * b1; acc[0][2] += a0 * b2; acc[0][3] += a0 * b3;
            acc[1][0] += a1 * b0; acc[1][1] += a1 * b1; acc[1][2] += a1 * b2; acc[1][3] += a1 * b3;
            acc[2][0] += a2 * b0; acc[2][1] += a2 * b1; acc[2][2] += a2 * b2; acc[2][3] += a2 * b3;
            acc[3][0] += a3 * b0; acc[3][1] += a3 * b1; acc[3][2] += a3 * b2; acc[3][3] += a3 * b3;
        }
    }
    #pragma unroll
    for (int i = 0; i < 4; ++i) {
        #pragma unroll
        for (int j = 0; j < 4; ++j) {
            int r = r0 + 4 * ty + i;   // b*64 + n
            int e = e0 + 4 * tx + j;   // h*64 + dh
            int b = r >> 6, n = r & 63, h = e >> 6, dh = e & 63;
            Out[(((size_t)(b * 8 + h) * 64 + n) * 64) + dh] = acc[i][j];
        }
    }
}

// ---------------- K2: scores + softmax -> Aperm[b,i,h*64+perm(j)] bf16 -----------
// K-slot permutation pi(c): slot c=hi*8+e holds k-offset (e<4 ? hi*4+e : 16+hi*4+e-4)
__global__ __launch_bounds__(256) void attn_softmax(
        const float* __restrict__ Qh, const float* __restrict__ Kh,
        u16* __restrict__ Aperm) {
    const int bh = blockIdx.x;          // b*8+h
    const int b = bh >> 3, h = bh & 7;
    const int tid = threadIdx.x;
    __shared__ float Qt[64][64];
    __shared__ float KT[64][65];
    const size_t base = (size_t)bh * 4096;
    #pragma unroll
    for (int rep = 0; rep < 16; ++rep) {
        int lin = rep * 256 + tid;
        int r = lin >> 6, c = lin & 63;
        Qt[r][c] = Qh[base + lin];
        KT[c][r] = Kh[base + lin];
    }
    __syncthreads();
    const int w = tid >> 6, lane = tid & 63;
    // inverse-permuted write position for k-offset w31 = lane&31
    const int w31 = lane & 31;
    const int slot = (w31 < 16) ? ((w31 >> 2) * 8 + (w31 & 3))
                                : (((w31 - 16) >> 2) * 8 + 4 + (w31 & 3));
    const int p = h * 64 + (lane & 32) + slot;
    for (int rr = 0; rr < 16; ++rr) {
        int i = w + 4 * rr;
        float s = 0.f;
        #pragma unroll
        for (int dd = 0; dd < 64; ++dd) s += Qt[i][dd] * KT[dd][lane];
        s *= 0.125f;                      // 1/(TAU*sqrt(DH))
        float m = s;
        #pragma unroll
        for (int off = 32; off; off >>= 1) m = fmaxf(m, __shfl_xor(m, off));
        float e = __expf(s - m);
        float sum = e;
        #pragma unroll
        for (int off = 32; off; off >>= 1) sum += __shfl_xor(sum, off);
        Aperm[((size_t)(b * 64 + i) << 9) + p] = f2bf(e / sum);
    }
}

// ---------------- K3: MFMA conv: v' = v@Wcat_h^T (LDS), V' = tril(Wconv)@v' ------
__global__ __launch_bounds__(256) void conv_mfma(
        const float* __restrict__ v, const float* __restrict__ Wconv,
        const float* __restrict__ Wcat, u16* __restrict__ Vp, int bbase) {
    const int bl = blockIdx.x, b = bbase + bl;
    const int hj = blockIdx.y, h = hj >> 6, j = hj & 63;
    const int tid = threadIdx.x;
    const int w = tid >> 6;            // wave id 0..3
    const int l = tid & 63;
    const int lo = l & 15, hi = l >> 4;

    // v' transposed [d][s] bf16, 16B-chunk XOR-swizzled: chunk' = (s>>3) ^ (d&7)
    __shared__ u16 vptB[64 * 256];     // 32 KB

    const size_t vbase = ((size_t)(b * 8 + h) * 64 + j) * 16384;

    // ---- Phase A: v'(256x64) = v(256x64) @ Wcat_h^T(64x64), MFMA 16x16x32 ----
    {
        f32x4 accA[4][4] = {};         // [s-tile][d-tile]; wave w owns s in [w*64, w*64+64)
        #pragma unroll
        for (int kk = 0; kk < 2; ++kk) {
            short8 bfr[4];
            #pragma unroll
            for (int di = 0; di < 4; ++di) {
                const float* p = Wcat + (size_t)(di * 16 + lo) * 512 + h * 64 + kk * 32 + hi * 8;
                bfr[di] = pack8(((const float4*)p)[0], ((const float4*)p)[1]);
            }
            #pragma unroll
            for (int si = 0; si < 4; ++si) {
                const float* p = v + vbase + (size_t)(w * 64 + si * 16 + lo) * 64 + kk * 32 + hi * 8;
                short8 af = pack8(((const float4*)p)[0], ((const float4*)p)[1]);
                #pragma unroll
                for (int di = 0; di < 4; ++di)
                    accA[si][di] = __builtin_amdgcn_mfma_f32_16x16x32_bf16(af, bfr[di], accA[si][di], 0, 0, 0);
            }
        }
        // write C transposed into vptB: s = w*64+si*16+hi*4+r, d = di*16+lo
        #pragma unroll
        for (int si = 0; si < 4; ++si) {
            int s0 = w * 64 + si * 16 + hi * 4;      // 4 consecutive s (s0 % 4 == 0)
            #pragma unroll
            for (int di = 0; di < 4; ++di) {
                int d = di * 16 + lo;
                u32 lo32 = (u32)f2bf(accA[si][di][0]) | ((u32)f2bf(accA[si][di][1]) << 16);
                u32 hi32 = (u32)f2bf(accA[si][di][2]) | ((u32)f2bf(accA[si][di][3]) << 16);
                u16* dst = &vptB[d * 256 + (((s0 >> 3) ^ (d & 7)) << 3) + (s0 & 7)];
                ((uint2*)dst)[0] = make_uint2(lo32, hi32);   // ds_write_b64
            }
        }
    }
    __syncthreads();

    // ---- Phase B: V'(256x64) = tril(Wconv_hj)(256x256) @ v'(256x64) ----
    // wave w owns t-tiles ti in {w, w+4, w+8, w+12} (balanced causal triangle)
    f32x4 acc[4][4] = {};              // [slot][d-tile]
    const float* wcb = Wconv + (size_t)hj * 65536;
    for (int kk = 0; kk < 8; ++kk) {   // s-chunk of 32
        if (2 * kk > w + 12) break;    // no active tile for this wave
        short8 bfr[4];
        #pragma unroll
        for (int di = 0; di < 4; ++di) {
            int d = di * 16 + lo;
            int sc = kk * 4 + hi;      // 8-wide s-chunk index
            bfr[di] = *(const short8*)&vptB[d * 256 + ((sc ^ (d & 7)) << 3)];  // ds_read_b128
        }
        #pragma unroll
        for (int slot = 0; slot < 4; ++slot) {
            int ti = w + slot * 4;
            if (ti < 2 * kk) continue;               // s_min > t_max: skip
            int t = ti * 16 + lo;
            const float* p = wcb + (size_t)t * 256 + kk * 32 + hi * 8;
            float4 x = ((const float4*)p)[0], y = ((const float4*)p)[1];
            float wf[8] = {x.x, x.y, x.z, x.w, y.x, y.y, y.z, y.w};
            if (ti <= 2 * kk + 1) {                  // diagonal chunk: mask s > t
                int sb = kk * 32 + hi * 8;
                #pragma unroll
                for (int e = 0; e < 8; ++e)
                    if (sb + e > t) wf[e] = 0.f;
            }
            short8 af;
            af[0] = (short)f2bf(wf[0]); af[1] = (short)f2bf(wf[1]);
            af[2] = (short)f2bf(wf[2]); af[3] = (short)f2bf(wf[3]);
            af[4] = (short)f2bf(wf[4]); af[5] = (short)f2bf(wf[5]);
            af[6] = (short)f2bf(wf[6]); af[7] = (short)f2bf(wf[7]);
            #pragma unroll
            for (int di = 0; di < 4; ++di)
                acc[slot][di] = __builtin_amdgcn_mfma_f32_16x16x32_bf16(af, bfr[di], acc[slot][di], 0, 0, 0);
        }
    }

    // write V' (bf16) to ws: vout[t*64 + d]
    u16* vout = Vp + ((size_t)bl * 512 + hj) * 16384;
    #pragma unroll
    for (int slot = 0; slot < 4; ++slot) {
        int ti = w + slot * 4;
        int t0 = ti * 16 + hi * 4;
        #pragma unroll
        for (int di = 0; di < 4; ++di) {
            int d = di * 16 + lo;
            #pragma unroll
            for (int r = 0; r < 4; ++r)
                vout[(size_t)(t0 + r) * 64 + d] = f2bf(acc[slot][di][r]);
        }
    }
}

// ---------------- K4: out[b](64x16384) = A(64x512) @ Vp(512x16384), MFMA ---------
// B-frags obtained by transposing Vp tiles in-register: D = mfma(X, Identity).
// Wave computes M=64 x N=32. Block: 4 waves -> N=128. Grid (128, bc).
__global__ __launch_bounds__(256) void final_mfma(
        const u16* __restrict__ Aperm, const u16* __restrict__ Vp,
        float* __restrict__ out, int bbase) {
    const int nblk = blockIdx.x;
    const int bl = blockIdx.y, b = bbase + bl;
    const int tid = threadIdx.x;
    const int w = tid >> 6, l = tid & 63;
    const int lo = l & 15, hi = l >> 4;
    const int nb = nblk * 128 + w * 32;

    // identity fragments (second operand): I1[w][c]=d(c==w), I2[w][c]=d(c==16+w)
    short8 I1, I2;
    #pragma unroll
    for (int e = 0; e < 8; ++e) {
        I1[e] = (hi * 8 + e == lo) ? (short)0x3F80 : (short)0;
        I2[e] = (hi * 8 + e == lo + 16) ? (short)0x3F80 : (short)0;
    }

    const u16* ab = Aperm + ((size_t)b << 15);               // b*64*512
    const u16* vb = Vp + (size_t)bl * 512 * 16384;

    f32x4 acc[4][2] = {};
    const f32x4 z = {};
    #pragma unroll 2
    for (int ks = 0; ks < 16; ++ks) {
        const int k0 = ks * 32;
        short8 af[4];
        #pragma unroll
        for (int mi = 0; mi < 4; ++mi)
            af[mi] = *(const short8*)&ab[(size_t)(mi * 16 + lo) * 512 + k0 + hi * 8];
        // X covers Vp[k0+{0..15}][nb+{0..31}] and [k0+{16..31}][...]
        short8 X1 = *(const short8*)&vb[(size_t)(k0 + lo) * 16384 + nb + hi * 8];
        short8 X2 = *(const short8*)&vb[(size_t)(k0 + 16 + lo) * 16384 + nb + hi * 8];
        f32x4 t1a = __builtin_amdgcn_mfma_f32_16x16x32_bf16(X1, I1, z, 0, 0, 0);
        f32x4 t1b = __builtin_amdgcn_mfma_f32_16x16x32_bf16(X1, I2, z, 0, 0, 0);
        f32x4 t2a = __builtin_amdgcn_mfma_f32_16x16x32_bf16(X2, I1, z, 0, 0, 0);
        f32x4 t2b = __builtin_amdgcn_mfma_f32_16x16x32_bf16(X2, I2, z, 0, 0, 0);
        short8 B0 = mk_bfrag(t1a, t2a);   // n-tile 0: lane holds Vp[k0+pi(c)][nb+lo]
        short8 B1 = mk_bfrag(t1b, t2b);   // n-tile 1: nb+16+lo
        #pragma unroll
        for (int mi = 0; mi < 4; ++mi) {
            acc[mi][0] = __builtin_amdgcn_mfma_f32_16x16x32_bf16(af[mi], B0, acc[mi][0], 0, 0, 0);
            acc[mi][1] = __builtin_amdgcn_mfma_f32_16x16x32_bf16(af[mi], B1, acc[mi][1], 0, 0, 0);
        }
    }

    float* ob = out + ((size_t)b << 20);                     // b*64*16384
    #pragma unroll
    for (int mi = 0; mi < 4; ++mi) {
        #pragma unroll
        for (int nt = 0; nt < 2; ++nt) {
            int td = nb + nt * 16 + lo;
            #pragma unroll
            for (int r = 0; r < 4; ++r) {
                int i = mi * 16 + hi * 4 + r;
                ob[(size_t)i * 16384 + td] = acc[mi][nt][r];
            }
        }
    }
}

extern "C" void kernel_launch(void* const* d_in, const int* in_sizes, int n_in,
                              void* d_out, int out_size, void* d_ws, size_t ws_size,
                              hipStream_t stream) {
    const float* q     = (const float*)d_in[0];
    const float* k     = (const float*)d_in[1];
    const float* v     = (const float*)d_in[2];
    const float* Wq    = (const float*)d_in[3];
    const float* Wk    = (const float*)d_in[4];
    const float* Wconv = (const float*)d_in[5];
    const float* Wcat  = (const float*)d_in[6];
    float* out = (float*)d_out;

    // ws layout: Aperm bf16 (512KB) | Qh (1MB) | Kh (1MB) | V' bf16 (up to 128MB)
    u16* Aperm = (u16*)d_ws;
    float* Qh = (float*)(Aperm + 262144);
    float* Kh = Qh + 262144;
    u16* Vp = (u16*)(Kh + 262144);
    const size_t fixed = 262144 * 2 + (size_t)2 * 262144 * 4;

    int bc = 8;  // batches per chunk; shrink if ws too small
    while (bc > 1 && fixed + (size_t)bc * 512 * 16384 * 2 > ws_size) bc >>= 1;

    proj_qk<<<dim3(8, 8, 2), 256, 0, stream>>>(q, k, Wq, Wk, Qh, Kh);
    attn_softmax<<<64, 256, 0, stream>>>(Qh, Kh, Aperm);
    for (int b0 = 0; b0 < 8; b0 += bc) {
        conv_mfma<<<dim3(bc, 512), 256, 0, stream>>>(v, Wconv, Wcat, Vp, b0);
        final_mfma<<<dim3(128, bc), 256, 0, stream>>>(Aperm, Vp, out, b0);
    }
}

// Round 4
// 252.751 us; speedup vs baseline: 3.9395x; 1.1769x over previous
//
#include <hip/hip_runtime.h>
#include <hip/hip_bf16.h>

// B=8 H=8 N=64 T=256 E=512 D=64 DH=64, TAU=1 -> scale 1/8
// Pipeline (reordered, exact same math as reference):
//   Qh = head-split(q@Wq^T), Kh = head-split(k@Wk^T)
//   Aperm[b,i,p]   = bf16 softmax_j(Qh.Kh^T/8), K-slot-permuted for MFMA frags
//   v'[b,h,j,s,d]  = sum_dd Wcat[d, h*64+dd] * v[b,h,j,s,dd]      (Wcat moved first; commutes)
//   V'[b,h,j,t,d]  = sum_{s<=t} Wconv[h,j,t,s] * v'[b,h,j,s,d]    (bf16 MFMA, reg-resident Wconv)
//   out[b,i,t,d]   = sum_{hj} A[i,hj] * V'[hj,td]  (MFMA; Vp transposed in-register via identity MFMA)

typedef unsigned short u16;
typedef unsigned int u32;
typedef __attribute__((ext_vector_type(8))) short short8;
typedef __attribute__((ext_vector_type(4))) float f32x4;

static __device__ __forceinline__ u16 f2bf(float f) {
    u32 x; __builtin_memcpy(&x, &f, 4);
    u32 r = (x + 0x7fffu + ((x >> 16) & 1u)) >> 16;  // RNE
    return (u16)r;
}
static __device__ __forceinline__ short8 pack8(float4 a, float4 b) {
    short8 r;
    r[0] = (short)f2bf(a.x); r[1] = (short)f2bf(a.y);
    r[2] = (short)f2bf(a.z); r[3] = (short)f2bf(a.w);
    r[4] = (short)f2bf(b.x); r[5] = (short)f2bf(b.y);
    r[6] = (short)f2bf(b.z); r[7] = (short)f2bf(b.w);
    return r;
}
// pack two transpose-MFMA outputs (exact bf16 in f32 high bits) into a B-frag
static __device__ __forceinline__ short8 mk_bfrag(f32x4 a, f32x4 b) {
    u32 w0 = (__float_as_uint(a[0]) >> 16) | (__float_as_uint(a[1]) & 0xffff0000u);
    u32 w1 = (__float_as_uint(a[2]) >> 16) | (__float_as_uint(a[3]) & 0xffff0000u);
    u32 w2 = (__float_as_uint(b[0]) >> 16) | (__float_as_uint(b[1]) & 0xffff0000u);
    u32 w3 = (__float_as_uint(b[2]) >> 16) | (__float_as_uint(b[3]) & 0xffff0000u);
    uint4 u = make_uint4(w0, w1, w2, w3);
    short8 r; __builtin_memcpy(&r, &u, 16); return r;
}

// ---------------- K1: Q/K projection, C = X(512x512) @ W^T, head-split store ----
__global__ __launch_bounds__(256) void proj_qk(
        const float* __restrict__ q, const float* __restrict__ k,
        const float* __restrict__ Wq, const float* __restrict__ Wk,
        float* __restrict__ Qh, float* __restrict__ Kh) {
    const int et = blockIdx.x, rt = blockIdx.y, z = blockIdx.z;
    const float* X = z ? k : q;
    const float* W = z ? Wk : Wq;
    float* Out = z ? Kh : Qh;
    __shared__ float Xs[32][65];
    __shared__ float Ws[32][65];
    const int tid = threadIdx.x;
    const int tx = tid & 15, ty = tid >> 4;
    const int r0 = rt * 64, e0 = et * 64;
    float acc[4][4] = {};
    for (int k0 = 0; k0 < 512; k0 += 32) {
        __syncthreads();
        #pragma unroll
        for (int rep = 0; rep < 8; ++rep) {
            int lin = rep * 256 + tid;
            int kk = lin & 31, m = lin >> 5;
            Xs[kk][m] = X[(size_t)(r0 + m) * 512 + k0 + kk];
            Ws[kk][m] = W[(size_t)(e0 + m) * 512 + k0 + kk];
        }
        __syncthreads();
        #pragma unroll 8
        for (int kk = 0; kk < 32; ++kk) {
            float a0 = Xs[kk][4 * ty + 0], a1 = Xs[kk][4 * ty + 1];
            float a2 = Xs[kk][4 * ty + 2], a3 = Xs[kk][4 * ty + 3];
            float b0 = Ws[kk][4 * tx + 0], b1 = Ws[kk][4 * tx + 1];
            float b2 = Ws[kk][4 * tx + 2], b3 = Ws[kk][4 * tx + 3];
            acc[0][0] += a0 * b0; acc[0][1] += a0 * b1; acc[0][2] += a0 * b2; acc[0][3] += a0 * b3;
            acc[1][0] += a1 * b0; acc[1][1] += a1 * b1; acc[1][2] += a1 * b2; acc[1][3] += a1 * b3;
            acc[2][0] += a2 * b0; acc[2][1] += a2 * b1; acc[2][2] += a2 * b2; acc[2][3] += a2 * b3;
            acc[3][0] += a3 * b0; acc[3][1] += a3 * b1; acc[3][2] += a3 * b2; acc[3][3] += a3 * b3;
        }
    }
    #pragma unroll
    for (int i = 0; i < 4; ++i) {
        #pragma unroll
        for (int j = 0; j < 4; ++j) {
            int r = r0 + 4 * ty + i;   // b*64 + n
            int e = e0 + 4 * tx + j;   // h*64 + dh
            int b = r >> 6, n = r & 63, h = e >> 6, dh = e & 63;
            Out[(((size_t)(b * 8 + h) * 64 + n) * 64) + dh] = acc[i][j];
        }
    }
}

// ---------------- K2: scores + softmax -> Aperm[b,i,h*64+perm(j)] bf16 -----------
__global__ __launch_bounds__(256) void attn_softmax(
        const float* __restrict__ Qh, const float* __restrict__ Kh,
        u16* __restrict__ Aperm) {
    const int bh = blockIdx.x;          // b*8+h
    const int b = bh >> 3, h = bh & 7;
    const int tid = threadIdx.x;
    __shared__ float Qt[64][64];
    __shared__ float KT[64][65];
    const size_t base = (size_t)bh * 4096;
    #pragma unroll
    for (int rep = 0; rep < 16; ++rep) {
        int lin = rep * 256 + tid;
        int r = lin >> 6, c = lin & 63;
        Qt[r][c] = Qh[base + lin];
        KT[c][r] = Kh[base + lin];
    }
    __syncthreads();
    const int w = tid >> 6, lane = tid & 63;
    const int w31 = lane & 31;
    const int slot = (w31 < 16) ? ((w31 >> 2) * 8 + (w31 & 3))
                                : (((w31 - 16) >> 2) * 8 + 4 + (w31 & 3));
    const int p = h * 64 + (lane & 32) + slot;
    for (int rr = 0; rr < 16; ++rr) {
        int i = w + 4 * rr;
        float s = 0.f;
        #pragma unroll
        for (int dd = 0; dd < 64; ++dd) s += Qt[i][dd] * KT[dd][lane];
        s *= 0.125f;                      // 1/(TAU*sqrt(DH))
        float m = s;
        #pragma unroll
        for (int off = 32; off; off >>= 1) m = fmaxf(m, __shfl_xor(m, off));
        float e = __expf(s - m);
        float sum = e;
        #pragma unroll
        for (int off = 32; off; off >>= 1) sum += __shfl_xor(sum, off);
        Aperm[((size_t)(b * 64 + i) << 9) + p] = f2bf(e / sum);
    }
}

// ---------------- K3: conv, one block per hj, batches looped ---------------------
// Wave w owns t-tiles {w, 7-w, 8+w, 15-w}: 18 triangular (ti,kk) tiles each.
template<int T0, int T1, int T2, int T3>
__device__ __forceinline__ void load_wconv(short8 wc[18], const float* __restrict__ wcb,
                                           int lo, int hi) {
    constexpr int tis[4]  = {T0, T1, T2, T3};
    constexpr int offs[4] = {0, T0/2+1, T0/2+1 + T1/2+1, T0/2+1 + T1/2+1 + T2/2+1};
    #pragma unroll
    for (int sl = 0; sl < 4; ++sl) {
        const int t = tis[sl] * 16 + lo;
        #pragma unroll
        for (int kk = 0; kk <= tis[sl] / 2; ++kk) {
            const float* p = wcb + (size_t)t * 256 + kk * 32 + hi * 8;
            float4 x = ((const float4*)p)[0], y = ((const float4*)p)[1];
            float wf[8] = {x.x, x.y, x.z, x.w, y.x, y.y, y.z, y.w};
            if (tis[sl] / 2 == kk) {               // diagonal tile: mask s > t
                int sb = kk * 32 + hi * 8;
                #pragma unroll
                for (int e = 0; e < 8; ++e)
                    if (sb + e > t) wf[e] = 0.f;
            }
            short8 af;
            #pragma unroll
            for (int e = 0; e < 8; ++e) af[e] = (short)f2bf(wf[e]);
            wc[offs[sl] + kk] = af;
        }
    }
}

template<int T0, int T1, int T2, int T3>
__device__ __forceinline__ void phaseB(const short8 wc[18], const u16* __restrict__ vptB,
                                       u16* __restrict__ vout, int lo, int hi) {
    constexpr int tis[4]  = {T0, T1, T2, T3};
    constexpr int offs[4] = {0, T0/2+1, T0/2+1 + T1/2+1, T0/2+1 + T1/2+1 + T2/2+1};
    constexpr int M01 = (T0 > T1 ? T0 : T1);
    constexpr int M23 = (T2 > T3 ? T2 : T3);
    constexpr int KM  = (M01 > M23 ? M01 : M23) / 2;
    f32x4 acc[4][4] = {};                          // [slot][di]
    #pragma unroll
    for (int kk = 0; kk <= KM; ++kk) {
        short8 bfr[4];
        #pragma unroll
        for (int di = 0; di < 4; ++di) {
            int d = di * 16 + lo;
            int sc = kk * 4 + hi;
            bfr[di] = *(const short8*)&vptB[d * 256 + ((sc ^ (d & 7)) << 3)];  // ds_read_b128
        }
        #pragma unroll
        for (int sl = 0; sl < 4; ++sl) {
            if (kk <= tis[sl] / 2) {
                #pragma unroll
                for (int di = 0; di < 4; ++di)
                    acc[sl][di] = __builtin_amdgcn_mfma_f32_16x16x32_bf16(
                        wc[offs[sl] + kk], bfr[di], acc[sl][di], 0, 0, 0);
            }
        }
    }
    #pragma unroll
    for (int sl = 0; sl < 4; ++sl) {
        int t0 = tis[sl] * 16 + hi * 4;
        #pragma unroll
        for (int di = 0; di < 4; ++di) {
            int d = di * 16 + lo;
            #pragma unroll
            for (int r = 0; r < 4; ++r)
                vout[(size_t)(t0 + r) * 64 + d] = f2bf(acc[sl][di][r]);
        }
    }
}

__global__ __launch_bounds__(256, 2) void conv_mfma(
        const float* __restrict__ v, const float* __restrict__ Wconv,
        const float* __restrict__ Wcat, u16* __restrict__ Vp, int b0, int bc) {
    const int hj = blockIdx.x, h = hj >> 6, j = hj & 63;
    const int tid = threadIdx.x;
    const int w = tid >> 6, l = tid & 63;
    const int lo = l & 15, hi = l >> 4;

    __shared__ u16 vptB[64 * 256];     // 32 KB: v'T[d][s], 16B-chunk XOR-swizzled

    // register-resident bf16 Wconv frags (18 tiles = 72 VGPR), loaded/masked once
    short8 wc[18];
    const float* wcb = Wconv + (size_t)hj * 65536;
    if (w == 0)      load_wconv<0, 7, 8, 15>(wc, wcb, lo, hi);
    else if (w == 1) load_wconv<1, 6, 9, 14>(wc, wcb, lo, hi);
    else if (w == 2) load_wconv<2, 5, 10, 13>(wc, wcb, lo, hi);
    else             load_wconv<3, 4, 11, 12>(wc, wcb, lo, hi);

    // register-resident Wcat B-frags (loaded once, reused all batches)
    short8 wcat[2][4];
    #pragma unroll
    for (int kk = 0; kk < 2; ++kk)
        #pragma unroll
        for (int di = 0; di < 4; ++di) {
            const float* p = Wcat + (size_t)(di * 16 + lo) * 512 + h * 64 + kk * 32 + hi * 8;
            wcat[kk][di] = pack8(((const float4*)p)[0], ((const float4*)p)[1]);
        }

    short8 staged[8];                  // v A-frags for current batch
    auto prefetch = [&](int b) {
        size_t vb = ((size_t)(b * 8 + h) * 64 + j) * 16384;
        #pragma unroll
        for (int kk = 0; kk < 2; ++kk)
            #pragma unroll
            for (int si = 0; si < 4; ++si) {
                const float* p = v + vb + (size_t)(w * 64 + si * 16 + lo) * 64 + kk * 32 + hi * 8;
                staged[kk * 4 + si] = pack8(((const float4*)p)[0], ((const float4*)p)[1]);
            }
    };
    prefetch(b0);

    for (int bi = 0; bi < bc; ++bi) {
        __syncthreads();               // phaseB(bi-1) LDS reads complete
        // ---- Phase A: v'(256x64) = v @ Wcat_h^T, si-streamed into LDS ----
        #pragma unroll
        for (int si = 0; si < 4; ++si) {
            f32x4 a4[4] = {};
            #pragma unroll
            for (int kk = 0; kk < 2; ++kk)
                #pragma unroll
                for (int di = 0; di < 4; ++di)
                    a4[di] = __builtin_amdgcn_mfma_f32_16x16x32_bf16(
                        staged[kk * 4 + si], wcat[kk][di], a4[di], 0, 0, 0);
            int s0 = w * 64 + si * 16 + hi * 4;
            #pragma unroll
            for (int di = 0; di < 4; ++di) {
                int d = di * 16 + lo;
                u32 lo32 = (u32)f2bf(a4[di][0]) | ((u32)f2bf(a4[di][1]) << 16);
                u32 hi32 = (u32)f2bf(a4[di][2]) | ((u32)f2bf(a4[di][3]) << 16);
                *(uint2*)&vptB[d * 256 + (((s0 >> 3) ^ (d & 7)) << 3) + (s0 & 7)] =
                    make_uint2(lo32, hi32);
            }
        }
        __syncthreads();               // v' visible to all waves
        if (bi + 1 < bc) prefetch(b0 + bi + 1);   // v-loads hide under phase B
        // ---- Phase B: V' = tril(Wconv) @ v', pure LDS+MFMA ----
        u16* vout = Vp + ((size_t)bi * 512 + hj) * 16384;
        if (w == 0)      phaseB<0, 7, 8, 15>(wc, vptB, vout, lo, hi);
        else if (w == 1) phaseB<1, 6, 9, 14>(wc, vptB, vout, lo, hi);
        else if (w == 2) phaseB<2, 5, 10, 13>(wc, vptB, vout, lo, hi);
        else             phaseB<3, 4, 11, 12>(wc, vptB, vout, lo, hi);
    }
}

// ---------------- K4: out[b](64x16384) = A(64x512) @ Vp(512x16384), MFMA ---------
__global__ __launch_bounds__(256) void final_mfma(
        const u16* __restrict__ Aperm, const u16* __restrict__ Vp,
        float* __restrict__ out, int bbase) {
    const int nblk = blockIdx.x;
    const int bl = blockIdx.y, b = bbase + bl;
    const int tid = threadIdx.x;
    const int w = tid >> 6, l = tid & 63;
    const int lo = l & 15, hi = l >> 4;
    const int nb = nblk * 128 + w * 32;

    short8 I1, I2;
    #pragma unroll
    for (int e = 0; e < 8; ++e) {
        I1[e] = (hi * 8 + e == lo) ? (short)0x3F80 : (short)0;
        I2[e] = (hi * 8 + e == lo + 16) ? (short)0x3F80 : (short)0;
    }

    const u16* ab = Aperm + ((size_t)b << 15);               // b*64*512
    const u16* vb = Vp + (size_t)bl * 512 * 16384;

    f32x4 acc[4][2] = {};
    const f32x4 z = {};
    #pragma unroll 2
    for (int ks = 0; ks < 16; ++ks) {
        const int k0 = ks * 32;
        short8 af[4];
        #pragma unroll
        for (int mi = 0; mi < 4; ++mi)
            af[mi] = *(const short8*)&ab[(size_t)(mi * 16 + lo) * 512 + k0 + hi * 8];
        short8 X1 = *(const short8*)&vb[(size_t)(k0 + lo) * 16384 + nb + hi * 8];
        short8 X2 = *(const short8*)&vb[(size_t)(k0 + 16 + lo) * 16384 + nb + hi * 8];
        f32x4 t1a = __builtin_amdgcn_mfma_f32_16x16x32_bf16(X1, I1, z, 0, 0, 0);
        f32x4 t1b = __builtin_amdgcn_mfma_f32_16x16x32_bf16(X1, I2, z, 0, 0, 0);
        f32x4 t2a = __builtin_amdgcn_mfma_f32_16x16x32_bf16(X2, I1, z, 0, 0, 0);
        f32x4 t2b = __builtin_amdgcn_mfma_f32_16x16x32_bf16(X2, I2, z, 0, 0, 0);
        short8 B0 = mk_bfrag(t1a, t2a);
        short8 B1 = mk_bfrag(t1b, t2b);
        #pragma unroll
        for (int mi = 0; mi < 4; ++mi) {
            acc[mi][0] = __builtin_amdgcn_mfma_f32_16x16x32_bf16(af[mi], B0, acc[mi][0], 0, 0, 0);
            acc[mi][1] = __builtin_amdgcn_mfma_f32_16x16x32_bf16(af[mi], B1, acc[mi][1], 0, 0, 0);
        }
    }

    float* ob = out + ((size_t)b << 20);                     // b*64*16384
    #pragma unroll
    for (int mi = 0; mi < 4; ++mi) {
        #pragma unroll
        for (int nt = 0; nt < 2; ++nt) {
            int td = nb + nt * 16 + lo;
            #pragma unroll
            for (int r = 0; r < 4; ++r) {
                int i = mi * 16 + hi * 4 + r;
                ob[(size_t)i * 16384 + td] = acc[mi][nt][r];
            }
        }
    }
}

extern "C" void kernel_launch(void* const* d_in, const int* in_sizes, int n_in,
                              void* d_out, int out_size, void* d_ws, size_t ws_size,
                              hipStream_t stream) {
    const float* q     = (const float*)d_in[0];
    const float* k     = (const float*)d_in[1];
    const float* v     = (const float*)d_in[2];
    const float* Wq    = (const float*)d_in[3];
    const float* Wk    = (const float*)d_in[4];
    const float* Wconv = (const float*)d_in[5];
    const float* Wcat  = (const float*)d_in[6];
    float* out = (float*)d_out;

    // ws layout: Aperm bf16 (512KB) | Qh (1MB) | Kh (1MB) | V' bf16 (up to 128MB)
    u16* Aperm = (u16*)d_ws;
    float* Qh = (float*)(Aperm + 262144);
    float* Kh = Qh + 262144;
    u16* Vp = (u16*)(Kh + 262144);
    const size_t fixed = 262144 * 2 + (size_t)2 * 262144 * 4;

    int bc = 8;  // batches per chunk; shrink if ws too small
    while (bc > 1 && fixed + (size_t)bc * 512 * 16384 * 2 > ws_size) bc >>= 1;

    proj_qk<<<dim3(8, 8, 2), 256, 0, stream>>>(q, k, Wq, Wk, Qh, Kh);
    attn_softmax<<<64, 256, 0, stream>>>(Qh, Kh, Aperm);
    for (int b0 = 0; b0 < 8; b0 += bc) {
        conv_mfma<<<dim3(512), 256, 0, stream>>>(v, Wconv, Wcat, Vp, b0, bc);
        final_mfma<<<dim3(128, bc), 256, 0, stream>>>(Aperm, Vp, out, b0);
    }
}